// Round 2
// baseline (425.989 us; speedup 1.0000x reference)
//
#include <hip/hip_runtime.h>
#include <math.h>

#define DD 256
#define BB 8
#define SS 1024
#define TAB_ELEMS 65536   // rcp table: 1/(idx+2), idx = i*256+j

__device__ __forceinline__ float vget(const float4& v, int jj) {
    switch (jj) { case 0: return v.x; case 1: return v.y; case 2: return v.z; default: return v.w; }
}

__global__ void fill_rcp_tab(float* __restrict__ tab) {
    int idx = blockIdx.x * 256 + threadIdx.x;
    tab[idx] = 1.0f / (float)(idx + 2);
}

// Block = 128 threads (2 waves), one s per block.
// Lane covers i = 64*r + lane, r = 0..3 (all 256 columns per wave).
// Matmul+LN: batch-split (wave h owns b in [4h, 4h+4), full j).
// Nk: j-split (wave h does j in [128h, 128h+128) for all 8 b), partials in LDS.
template<bool USE_TAB>
__global__ __launch_bounds__(128, 2)
void fused_hierddpm(const float* __restrict__ seq,
                    const float* __restrict__ M1, const float* __restrict__ P1,
                    const float* __restrict__ g1, const float* __restrict__ be1,
                    const float* __restrict__ M2, const float* __restrict__ P2,
                    const float* __restrict__ g2, const float* __restrict__ be2,
                    const float* __restrict__ rcp_tab,
                    float* __restrict__ out)
{
    __shared__ float xs[BB][DD];          // layer input (residual source)
    __shared__ float xt[BB][DD];          // post-LN x_trans
    __shared__ float accp[2][BB][DD];     // Nk partials per wave

    const int s    = blockIdx.x;
    const int tid  = threadIdx.x;
    const int h    = tid >> 6;            // wave id 0/1
    const int lane = tid & 63;
    const float kf = (float)s;

    // ---- stage x[b, s, :] into LDS, float4-coalesced
    {
        const float4* seq4 = (const float4*)seq;
        float4* xs4 = (float4*)xs;
        #pragma unroll
        for (int q = 0; q < 4; ++q) {
            int v  = tid + 128 * q;           // float4 index 0..511
            int b  = v >> 6;
            int j4 = v & 63;
            xs4[v] = seq4[((size_t)b * SS + s) * 64 + j4];
        }
    }
    __syncthreads();

    #pragma unroll 1
    for (int layer = 0; layer < 2; ++layer) {
        const float* M  = layer ? M2  : M1;
        const float* P  = layer ? P2  : P1;
        const float* g  = layer ? g2  : g1;
        const float* be = layer ? be2 : be1;

        // ---- x @ M.T for owned batch rows b = 4h+q, output cols i = 64r+lane
        float m[4][4];                        // [r][q]
        #pragma unroll
        for (int r = 0; r < 4; ++r)
            #pragma unroll
            for (int q = 0; q < 4; ++q) m[r][q] = 0.f;

        const float4* M4 = (const float4*)M;
        #pragma unroll 2
        for (int j4 = 0; j4 < 64; ++j4) {
            float4 xv[4], mv[4];
            #pragma unroll
            for (int q = 0; q < 4; ++q)
                xv[q] = ((const float4*)xs[4 * h + q])[j4];
            #pragma unroll
            for (int r = 0; r < 4; ++r)
                mv[r] = M4[(size_t)(64 * r + lane) * 64 + j4];
            #pragma unroll
            for (int r = 0; r < 4; ++r)
                #pragma unroll
                for (int q = 0; q < 4; ++q) {
                    m[r][q] = fmaf(mv[r].x, xv[q].x, m[r][q]);
                    m[r][q] = fmaf(mv[r].y, xv[q].y, m[r][q]);
                    m[r][q] = fmaf(mv[r].z, xv[q].z, m[r][q]);
                    m[r][q] = fmaf(mv[r].w, xv[q].w, m[r][q]);
                }
        }

        // ---- LayerNorm for owned b rows (wave-local: full i range in regs)
        float gv[4], bev[4];
        #pragma unroll
        for (int r = 0; r < 4; ++r) {
            gv[r]  = g[64 * r + lane];
            bev[r] = be[64 * r + lane];
        }
        #pragma unroll
        for (int q = 0; q < 4; ++q) {
            float sum = 0.f, ssq = 0.f;
            #pragma unroll
            for (int r = 0; r < 4; ++r) {
                sum += m[r][q];
                ssq  = fmaf(m[r][q], m[r][q], ssq);
            }
            #pragma unroll
            for (int off = 32; off >= 1; off >>= 1) {
                sum += __shfl_xor(sum, off, 64);
                ssq += __shfl_xor(ssq, off, 64);
            }
            float mu  = sum * (1.f / DD);
            float var = ssq * (1.f / DD) - mu * mu;
            float rs  = rsqrtf(var + 1e-5f);
            #pragma unroll
            for (int r = 0; r < 4; ++r) {
                float v = fmaf((m[r][q] - mu) * rs, gv[r], bev[r]);
                xt[4 * h + q][64 * r + lane] = v;
            }
        }
        __syncthreads();

        // ---- Nk partial: wave h covers j in [128h, 128h+128) for all 8 b
        float acc[4][BB];                     // [r][b]
        #pragma unroll
        for (int r = 0; r < 4; ++r)
            #pragma unroll
            for (int b = 0; b < BB; ++b)
                acc[r][b] = (h == 0) ? xs[b][64 * r + lane] : 0.f;  // residual in wave 0

        const float4* P4 = (const float4*)P;
        const float4* T4 = (const float4*)rcp_tab;
        float pb[4];
        #pragma unroll
        for (int r = 0; r < 4; ++r) pb[r] = (float)((64 * r + lane) * DD + 2);

        const int j4lo = 32 * h;
        #pragma unroll 2
        for (int j4i = 0; j4i < 32; ++j4i) {
            const int j4 = j4lo + j4i;
            float4 xv[BB];
            #pragma unroll
            for (int b = 0; b < BB; ++b)
                xv[b] = ((const float4*)xt[b])[j4];
            float4 pv[4], rt[4];
            #pragma unroll
            for (int r = 0; r < 4; ++r) {
                size_t rowoff = (size_t)(64 * r + lane) * 64 + j4;
                pv[r] = P4[rowoff];
                if (USE_TAB) rt[r] = T4[rowoff];
            }
            const float jbase = (float)(4 * j4);
            #pragma unroll
            for (int jj = 0; jj < 4; ++jj) {
                float w[4];
                #pragma unroll
                for (int r = 0; r < 4; ++r) {
                    float t;
                    if (USE_TAB) {
                        t = kf * vget(rt[r], jj);
                    } else {
                        float pf = pb[r] + jbase + (float)jj;
                        t = kf * __builtin_amdgcn_rcpf(pf);
                    }
                    float f = __builtin_amdgcn_fractf(t);
                    float c = __builtin_amdgcn_cosf(f);
                    w[r] = vget(pv[r], jj) * c;
                }
                #pragma unroll
                for (int b = 0; b < BB; ++b) {
                    float xtv = vget(xv[b], jj);
                    #pragma unroll
                    for (int r = 0; r < 4; ++r)
                        acc[r][b] = fmaf(w[r], xtv, acc[r][b]);
                }
            }
        }

        #pragma unroll
        for (int r = 0; r < 4; ++r)
            #pragma unroll
            for (int b = 0; b < BB; ++b)
                accp[h][b][64 * r + lane] = acc[r][b];
        __syncthreads();

        // ---- combine partials
        const float* a0 = (const float*)accp[0];
        const float* a1 = (const float*)accp[1];
        if (layer == 0) {
            float* xsf = (float*)xs;
            #pragma unroll
            for (int e = tid; e < BB * DD; e += 128)
                xsf[e] = a0[e] + a1[e];
            __syncthreads();
        } else {
            #pragma unroll
            for (int e = tid; e < BB * DD; e += 128) {
                int b = e >> 8, i = e & 255;
                out[((size_t)b * SS + s) * DD + i] = a0[e] + a1[e];
            }
        }
    }
}

extern "C" void kernel_launch(void* const* d_in, const int* in_sizes, int n_in,
                              void* d_out, int out_size, void* d_ws, size_t ws_size,
                              hipStream_t stream)
{
    const float* seq = (const float*)d_in[0];
    const float* M1  = (const float*)d_in[1];
    const float* P1  = (const float*)d_in[2];
    const float* g1  = (const float*)d_in[3];
    const float* b1  = (const float*)d_in[4];
    const float* M2  = (const float*)d_in[5];
    const float* P2  = (const float*)d_in[6];
    const float* g2  = (const float*)d_in[7];
    const float* b2  = (const float*)d_in[8];
    float* out = (float*)d_out;

    if (ws_size >= (size_t)TAB_ELEMS * sizeof(float)) {
        float* tab = (float*)d_ws;
        fill_rcp_tab<<<TAB_ELEMS / 256, 256, 0, stream>>>(tab);
        fused_hierddpm<true><<<SS, 128, 0, stream>>>(seq, M1, P1, g1, b1,
                                                     M2, P2, g2, b2, tab, out);
    } else {
        fused_hierddpm<false><<<SS, 128, 0, stream>>>(seq, M1, P1, g1, b1,
                                                      M2, P2, g2, b2, nullptr, out);
    }
}

// Round 3
// 186.276 us; speedup vs baseline: 2.2869x; 2.2869x over previous
//
#include <hip/hip_runtime.h>
#include <math.h>

#define DD 256
#define BB 8
#define SS 1024
#define STB 2              // s per block (and per wave, in registers)

__device__ __forceinline__ float vget(const float4& v, int jj) {
    switch (jj) { case 0: return v.x; case 1: return v.y; case 2: return v.z; default: return v.w; }
}

// Block = 512 threads (8 waves). Block owns s0=2*bid, s1=s0+1.
// Wave h: iq = h&3 (i-rows 64*iq+lane), jh = h>>2 (j-half).
// Each wave processes BOTH s from the same M/P register loads.
// Matmul and Nk are j-split -> partials combined through LDS.
__global__ __launch_bounds__(512, 4)
void fused_hierddpm(const float* __restrict__ seq,
                    const float* __restrict__ M1, const float* __restrict__ P1,
                    const float* __restrict__ g1, const float* __restrict__ be1,
                    const float* __restrict__ M2, const float* __restrict__ P2,
                    const float* __restrict__ g2, const float* __restrict__ be2,
                    float* __restrict__ out)
{
    __shared__ float xs[STB][BB][DD];          // layer input / residual
    __shared__ float xt[STB][BB][DD];          // post-LN x_trans
    __shared__ float part[2][STB][BB][DD];     // j-half partials

    const int tid  = threadIdx.x;
    const int h    = tid >> 6;
    const int lane = tid & 63;
    const int iq   = h & 3;          // i-quarter
    const int jh   = h >> 2;         // j-half
    const int row  = 64 * iq + lane; // this lane's output row i
    const int s0   = blockIdx.x * STB;

    // ---- stage x[b, s0+st, :] into LDS, float4-coalesced
    {
        const float4* seq4 = (const float4*)seq;
        float4* xs4 = (float4*)xs;
        #pragma unroll
        for (int w = 0; w < 2; ++w) {
            int v  = tid + 512 * w;            // 0..1023
            int st = v >> 9;                   // /(BB*64)
            int rm = v & 511;
            int b  = rm >> 6, j4 = rm & 63;
            xs4[v] = seq4[((size_t)b * SS + s0 + st) * 64 + j4];
        }
    }
    __syncthreads();

    #pragma unroll 1
    for (int layer = 0; layer < 2; ++layer) {
        const float* M  = layer ? M2  : M1;
        const float* P  = layer ? P2  : P1;
        const float* g  = layer ? g2  : g1;
        const float* be = layer ? be2 : be1;

        // ======== matmul partial: rows i=row, j in this wave's half, both s
        {
            float m[STB][BB];
            #pragma unroll
            for (int st = 0; st < STB; ++st)
                #pragma unroll
                for (int b = 0; b < BB; ++b) m[st][b] = 0.f;

            const float4* Mrow = (const float4*)M + (size_t)row * 64 + 32 * jh;
            const float4* xs4c = (const float4*)xs;
            #pragma unroll 4
            for (int t4 = 0; t4 < 32; ++t4) {
                const int j4 = 32 * jh + t4;
                float4 mv = Mrow[t4];
                #pragma unroll
                for (int st = 0; st < STB; ++st) {
                    float4 xv[BB];
                    #pragma unroll
                    for (int b = 0; b < BB; ++b)
                        xv[b] = xs4c[(st * BB + b) * 64 + j4];   // LDS broadcast
                    #pragma unroll
                    for (int b = 0; b < BB; ++b) {
                        m[st][b] = fmaf(mv.x, xv[b].x, m[st][b]);
                        m[st][b] = fmaf(mv.y, xv[b].y, m[st][b]);
                        m[st][b] = fmaf(mv.z, xv[b].z, m[st][b]);
                        m[st][b] = fmaf(mv.w, xv[b].w, m[st][b]);
                    }
                }
            }
            #pragma unroll
            for (int st = 0; st < STB; ++st)
                #pragma unroll
                for (int b = 0; b < BB; ++b)
                    part[jh][st][b][row] = m[st][b];
        }
        __syncthreads();

        // ======== combine partials + LayerNorm: wave h -> (st=h&1, b-pair=h>>1)
        {
            const int st = h & 1;
            const int bp = h >> 1;
            float gv[4], bev[4];
            #pragma unroll
            for (int r = 0; r < 4; ++r) {
                gv[r]  = g[lane + 64 * r];
                bev[r] = be[lane + 64 * r];
            }
            #pragma unroll
            for (int q = 0; q < 2; ++q) {
                const int b = 2 * bp + q;
                float v[4], sum = 0.f, ssq = 0.f;
                #pragma unroll
                for (int r = 0; r < 4; ++r) {
                    int i = lane + 64 * r;
                    v[r] = part[0][st][b][i] + part[1][st][b][i];
                    sum += v[r];
                    ssq  = fmaf(v[r], v[r], ssq);
                }
                #pragma unroll
                for (int off = 32; off >= 1; off >>= 1) {
                    sum += __shfl_xor(sum, off, 64);
                    ssq += __shfl_xor(ssq, off, 64);
                }
                float mu  = sum * (1.f / DD);
                float var = ssq * (1.f / DD) - mu * mu;
                float rs  = rsqrtf(var + 1e-5f);
                #pragma unroll
                for (int r = 0; r < 4; ++r) {
                    int i = lane + 64 * r;
                    xt[st][b][i] = fmaf((v[r] - mu) * rs, gv[r], bev[r]);
                }
            }
        }
        __syncthreads();

        // ======== Nk partial: rows i=row, this wave's j-half, both s.
        // invp (rcp) and P row shared across both s in registers.
        {
            float acc[STB][BB];
            #pragma unroll
            for (int st = 0; st < STB; ++st)
                #pragma unroll
                for (int b = 0; b < BB; ++b) acc[st][b] = 0.f;

            const float4* Prow = (const float4*)P + (size_t)row * 64 + 32 * jh;
            const float4* xt4  = (const float4*)xt;
            const float pbase = (float)(row * DD + 2 + 128 * jh);

            #pragma unroll 2
            for (int t4 = 0; t4 < 32; ++t4) {
                const int j4 = 32 * jh + t4;
                float4 pv = Prow[t4];
                const float jb = pbase + (float)(4 * t4);
                float invp[4];
                #pragma unroll
                for (int jj = 0; jj < 4; ++jj)
                    invp[jj] = __builtin_amdgcn_rcpf(jb + (float)jj);
                #pragma unroll
                for (int st = 0; st < STB; ++st) {
                    float4 xv[BB];
                    #pragma unroll
                    for (int b = 0; b < BB; ++b)
                        xv[b] = xt4[(st * BB + b) * 64 + j4];    // LDS broadcast
                    const float kf = (float)(s0 + st);
                    #pragma unroll
                    for (int jj = 0; jj < 4; ++jj) {
                        float f = __builtin_amdgcn_fractf(kf * invp[jj]);
                        float c = __builtin_amdgcn_cosf(f);
                        float w = vget(pv, jj) * c;
                        #pragma unroll
                        for (int b = 0; b < BB; ++b)
                            acc[st][b] = fmaf(w, vget(xv[b], jj), acc[st][b]);
                    }
                }
            }
            #pragma unroll
            for (int st = 0; st < STB; ++st)
                #pragma unroll
                for (int b = 0; b < BB; ++b)
                    part[jh][st][b][row] = acc[st][b];
        }
        __syncthreads();

        // ======== combine Nk partials + residual; write xs (layer 0) or out
        {
            const int st = h & 1;
            const int bp = h >> 1;
            #pragma unroll
            for (int q = 0; q < 2; ++q) {
                const int b = 2 * bp + q;
                #pragma unroll
                for (int r = 0; r < 4; ++r) {
                    int i = lane + 64 * r;
                    float val = part[0][st][b][i] + part[1][st][b][i] + xs[st][b][i];
                    if (layer == 0) xs[st][b][i] = val;
                    else out[((size_t)b * SS + s0 + st) * DD + i] = val;
                }
            }
        }
        if (layer == 0) __syncthreads();
    }
}

extern "C" void kernel_launch(void* const* d_in, const int* in_sizes, int n_in,
                              void* d_out, int out_size, void* d_ws, size_t ws_size,
                              hipStream_t stream)
{
    const float* seq = (const float*)d_in[0];
    const float* M1  = (const float*)d_in[1];
    const float* P1  = (const float*)d_in[2];
    const float* g1  = (const float*)d_in[3];
    const float* b1  = (const float*)d_in[4];
    const float* M2  = (const float*)d_in[5];
    const float* P2  = (const float*)d_in[6];
    const float* g2  = (const float*)d_in[7];
    const float* b2  = (const float*)d_in[8];
    float* out = (float*)d_out;

    fused_hierddpm<<<SS / STB, 512, 0, stream>>>(seq, M1, P1, g1, b1,
                                                 M2, P2, g2, b2, out);
}

// Round 4
// 162.113 us; speedup vs baseline: 2.6277x; 1.1490x over previous
//
#include <hip/hip_runtime.h>

#define DD 256
#define BB 8
#define SS 1024

typedef __attribute__((ext_vector_type(8))) short short8;
typedef __attribute__((ext_vector_type(4))) float float4v;

// round-to-nearest-even fp32 -> bf16 pair packed into u32 (a=low, b=high)
__device__ __forceinline__ unsigned bf16pair(float a, float b) {
    unsigned ua = __float_as_uint(a), ub = __float_as_uint(b);
    ua += 0x7FFFu + ((ua >> 16) & 1u);
    ub += 0x7FFFu + ((ub >> 16) & 1u);
    return (ua >> 16) | (ub & 0xFFFF0000u);
}
__device__ __forceinline__ unsigned short bf16one(float a) {
    unsigned ua = __float_as_uint(a);
    ua += 0x7FFFu + ((ua >> 16) & 1u);
    return (unsigned short)(ua >> 16);
}

// Block = 256 threads (4 waves), handles s0=2*bid and s0+1.
// A-matrix rows r = sl*8 + b (16 rows). Wave w owns n-tiles 4w..4w+3.
// W slab LDS stride = 40 bf16 (80 B row: 16B-aligned frags, spread banks).
#define WSTRIDE 40
#define XSTRIDE 264

__global__ __launch_bounds__(256, 2)
void fused_hierddpm(const float* __restrict__ seq,
                    const float* __restrict__ M1, const float* __restrict__ P1,
                    const float* __restrict__ g1, const float* __restrict__ be1,
                    const float* __restrict__ M2, const float* __restrict__ P2,
                    const float* __restrict__ g2, const float* __restrict__ be2,
                    float* __restrict__ out)
{
    __shared__ float xs[2][BB][DD];                          // 16384 B residual fp32
    __shared__ __align__(16) unsigned short xtb[16][XSTRIDE]; // 8448 B LN'd xt bf16
    __shared__ float stats[4][16][2];                        // 512 B
    __shared__ __align__(16) unsigned short Wbuf[2 * 256 * WSTRIDE]; // 40960 B (hosts xsb too)

    unsigned short (*xsb)[XSTRIDE] = (unsigned short (*)[XSTRIDE])Wbuf;

    const int tid  = threadIdx.x;
    const int w    = tid >> 6;
    const int lane = tid & 63;
    const int l15  = lane & 15;
    const int quad = lane >> 4;
    const int s0   = blockIdx.x * 2;
    const float k0 = (float)s0, k1 = (float)(s0 + 1);

    // ---- stage x into xs (fp32) and xsb (bf16 A-layout rows r=sl*8+b)
    {
        const float4* seq4 = (const float4*)seq;
        #pragma unroll
        for (int u = 0; u < 4; ++u) {
            int v  = tid + 256 * u;          // float4 index 0..1023
            int sl = v >> 9;
            int rm = v & 511;
            int b  = rm >> 6, j4 = rm & 63;
            float4 x = seq4[((size_t)b * SS + s0 + sl) * 64 + j4];
            ((float4*)xs)[v] = x;
            unsigned* dst = (unsigned*)&xsb[sl * 8 + b][4 * j4];
            dst[0] = bf16pair(x.x, x.y);
            dst[1] = bf16pair(x.z, x.w);
        }
    }
    __syncthreads();

    #pragma unroll 1
    for (int layer = 0; layer < 2; ++layer) {
        const float* M  = layer ? M2  : M1;
        const float* P  = layer ? P2  : P1;
        const float* g  = layer ? g2  : g1;
        const float* be = layer ? be2 : be1;

        // ======== phase A: xt = x @ M^T (MFMA), wave owns n-tiles 4w..4w+3
        float4v acc1[4];
        #pragma unroll
        for (int nt = 0; nt < 4; ++nt) acc1[nt] = (float4v){0.f, 0.f, 0.f, 0.f};

        #pragma unroll 1
        for (int kt = 0; kt < 8; ++kt) {
            short8 a = *(const short8*)&xsb[l15][kt * 32 + quad * 8];
            #pragma unroll
            for (int nt = 0; nt < 4; ++nt) {
                int n0 = 16 * (4 * w + nt);
                const float4* Mr = (const float4*)M +
                    ((size_t)(n0 + l15) * 64 + kt * 8 + quad * 2);
                float4 m0 = Mr[0], m1 = Mr[1];
                union { short8 s; unsigned u[4]; } bb;
                bb.u[0] = bf16pair(m0.x, m0.y);
                bb.u[1] = bf16pair(m0.z, m0.w);
                bb.u[2] = bf16pair(m1.x, m1.y);
                bb.u[3] = bf16pair(m1.z, m1.w);
                acc1[nt] = __builtin_amdgcn_mfma_f32_16x16x32_bf16(a, bb.s, acc1[nt], 0, 0, 0);
            }
        }

        // ======== LayerNorm in C-register layout (row m = quad*4+reg)
        {
            float rsum[4], rssq[4];
            #pragma unroll
            for (int reg = 0; reg < 4; ++reg) {
                float sm = 0.f, sq = 0.f;
                #pragma unroll
                for (int nt = 0; nt < 4; ++nt) {
                    float v = acc1[nt][reg];
                    sm += v;
                    sq  = fmaf(v, v, sq);
                }
                #pragma unroll
                for (int off = 1; off < 16; off <<= 1) {
                    sm += __shfl_xor(sm, off, 64);
                    sq += __shfl_xor(sq, off, 64);
                }
                rsum[reg] = sm; rssq[reg] = sq;
            }
            if (l15 == 0) {
                #pragma unroll
                for (int reg = 0; reg < 4; ++reg) {
                    stats[w][quad * 4 + reg][0] = rsum[reg];
                    stats[w][quad * 4 + reg][1] = rssq[reg];
                }
            }
        }
        __syncthreads();
        {
            float mu[4], rs[4];
            #pragma unroll
            for (int reg = 0; reg < 4; ++reg) {
                int m = quad * 4 + reg;
                float sm = stats[0][m][0] + stats[1][m][0] + stats[2][m][0] + stats[3][m][0];
                float sq = stats[0][m][1] + stats[1][m][1] + stats[2][m][1] + stats[3][m][1];
                float mm = sm * (1.f / DD);
                mu[reg] = mm;
                rs[reg] = rsqrtf(sq * (1.f / DD) - mm * mm + 1e-5f);
            }
            #pragma unroll
            for (int nt = 0; nt < 4; ++nt) {
                int col = 16 * (4 * w + nt) + l15;
                float gv = g[col], bv = be[col];
                #pragma unroll
                for (int reg = 0; reg < 4; ++reg) {
                    float v = fmaf((acc1[nt][reg] - mu[reg]) * rs[reg], gv, bv);
                    xtb[quad * 4 + reg][col] = bf16one(v);
                }
            }
        }
        __syncthreads();   // xtb ready; xsb (in Wbuf) dead -> W gen may write

        // ======== phase B: Nk = xt @ W_s^T, W generated per 32-j slab
        float4v accS[2][4];
        #pragma unroll
        for (int sl = 0; sl < 2; ++sl)
            #pragma unroll
            for (int nt = 0; nt < 4; ++nt) accS[sl][nt] = (float4v){0.f, 0.f, 0.f, 0.f};

        #pragma unroll 1
        for (int kt = 0; kt < 8; ++kt) {
            // ---- generate W_{s0},W_{s1} for j in [32kt, 32kt+32)
            {
                const int j4 = tid & 7;        // 0..7 (fast: coalesced P rows)
                const int i0 = tid >> 3;       // 0..31
                #pragma unroll
                for (int v = 0; v < 8; ++v) {
                    int i = 32 * v + i0;
                    float4 pv = *(const float4*)(P + (size_t)i * 256 + kt * 32 + j4 * 4);
                    float pb = (float)(i * 256 + kt * 32 + j4 * 4 + 2);
                    float c0[4], c1[4];
                    #pragma unroll
                    for (int e = 0; e < 4; ++e) {
                        float invp = __builtin_amdgcn_rcpf(pb + (float)e);
                        c0[e] = __builtin_amdgcn_cosf(__builtin_amdgcn_fractf(k0 * invp));
                        c1[e] = __builtin_amdgcn_cosf(__builtin_amdgcn_fractf(k1 * invp));
                    }
                    unsigned* d0 = (unsigned*)&Wbuf[(size_t)i * WSTRIDE + 4 * j4];
                    d0[0] = bf16pair(pv.x * c0[0], pv.y * c0[1]);
                    d0[1] = bf16pair(pv.z * c0[2], pv.w * c0[3]);
                    unsigned* d1 = (unsigned*)&Wbuf[(size_t)(256 + i) * WSTRIDE + 4 * j4];
                    d1[0] = bf16pair(pv.x * c1[0], pv.y * c1[1]);
                    d1[1] = bf16pair(pv.z * c1[2], pv.w * c1[3]);
                }
            }
            __syncthreads();

            // ---- MFMA: rows 0-7 valid vs W_{s0}, rows 8-15 valid vs W_{s1}
            {
                short8 a = *(const short8*)&xtb[l15][kt * 32 + quad * 8];
                #pragma unroll
                for (int nt = 0; nt < 4; ++nt) {
                    int n0 = 16 * (4 * w + nt);
                    short8 b0 = *(const short8*)&Wbuf[(size_t)(n0 + l15) * WSTRIDE + quad * 8];
                    short8 b1 = *(const short8*)&Wbuf[(size_t)(256 + n0 + l15) * WSTRIDE + quad * 8];
                    accS[0][nt] = __builtin_amdgcn_mfma_f32_16x16x32_bf16(a, b0, accS[0][nt], 0, 0, 0);
                    accS[1][nt] = __builtin_amdgcn_mfma_f32_16x16x32_bf16(a, b1, accS[1][nt], 0, 0, 0);
                }
            }
            __syncthreads();   // protect Wbuf before next slab's gen
        }

        // ======== epilogue: select valid s-half per quad, add residual
        #pragma unroll
        for (int nt = 0; nt < 4; ++nt) {
            int col = 16 * (4 * w + nt) + l15;
            float4v av = (quad < 2) ? accS[0][nt] : accS[1][nt];
            int sl = quad >> 1;
            #pragma unroll
            for (int reg = 0; reg < 4; ++reg) {
                int m = quad * 4 + reg;
                int b = m & 7;
                float val = av[reg] + xs[sl][b][col];
                if (layer == 0) {
                    xs[sl][b][col]  = val;
                    xsb[m][col]     = bf16one(val);
                } else {
                    out[((size_t)b * SS + s0 + sl) * DD + col] = val;
                }
            }
        }
        if (layer == 0) __syncthreads();
    }
}

extern "C" void kernel_launch(void* const* d_in, const int* in_sizes, int n_in,
                              void* d_out, int out_size, void* d_ws, size_t ws_size,
                              hipStream_t stream)
{
    const float* seq = (const float*)d_in[0];
    const float* M1  = (const float*)d_in[1];
    const float* P1  = (const float*)d_in[2];
    const float* g1  = (const float*)d_in[3];
    const float* b1  = (const float*)d_in[4];
    const float* M2  = (const float*)d_in[5];
    const float* P2  = (const float*)d_in[6];
    const float* g2  = (const float*)d_in[7];
    const float* b2  = (const float*)d_in[8];
    float* out = (float*)d_out;

    fused_hierddpm<<<SS / 2, 256, 0, stream>>>(seq, M1, P1, g1, b1,
                                               M2, P2, g2, b2, out);
}

// Round 5
// 158.501 us; speedup vs baseline: 2.6876x; 1.0228x over previous
//
#include <hip/hip_runtime.h>

#define DD 256
#define BB 8
#define SS 1024
#define XSTRIDE 264

typedef __attribute__((ext_vector_type(8))) short short8;
typedef __attribute__((ext_vector_type(4))) float float4v;

// round-to-nearest-even fp32 -> bf16 pair packed into u32 (a=low, b=high)
__device__ __forceinline__ unsigned bf16pair(float a, float b) {
    unsigned ua = __float_as_uint(a), ub = __float_as_uint(b);
    ua += 0x7FFFu + ((ua >> 16) & 1u);
    ub += 0x7FFFu + ((ub >> 16) & 1u);
    return (ua >> 16) | (ub & 0xFFFF0000u);
}
__device__ __forceinline__ unsigned short bf16one(float a) {
    unsigned ua = __float_as_uint(a);
    ua += 0x7FFFu + ((ua >> 16) & 1u);
    return (unsigned short)(ua >> 16);
}

// Block = 256 threads (4 waves), handles s0=2*bid and s0+1.
// A-matrix rows r = sl*8 + b (16 rows). Wave w owns n-tiles 4w..4w+3.
// Phase B: W_s B-fragments are generated IN REGISTERS (each W element is
// consumed by exactly one fragment of one wave -> no LDS staging, no barriers).
__global__ __launch_bounds__(256, 4)
void fused_hierddpm(const float* __restrict__ seq,
                    const float* __restrict__ M1, const float* __restrict__ P1,
                    const float* __restrict__ g1, const float* __restrict__ be1,
                    const float* __restrict__ M2, const float* __restrict__ P2,
                    const float* __restrict__ g2, const float* __restrict__ be2,
                    float* __restrict__ out)
{
    __shared__ float xs[2][BB][DD];                           // 16384 B residual fp32
    __shared__ __align__(16) unsigned short xsb[16][XSTRIDE]; // 8448 B input bf16 (A-layout)
    __shared__ __align__(16) unsigned short xtb[16][XSTRIDE]; // 8448 B LN'd xt bf16
    __shared__ float stats[4][16][2];                         // 512 B

    const int tid  = threadIdx.x;
    const int w    = tid >> 6;
    const int lane = tid & 63;
    const int l15  = lane & 15;
    const int quad = lane >> 4;
    const int s0   = blockIdx.x * 2;
    const float k0 = (float)s0, k1 = (float)(s0 + 1);

    // ---- stage x into xs (fp32) and xsb (bf16 A-layout rows r = sl*8+b)
    {
        const float4* seq4 = (const float4*)seq;
        #pragma unroll
        for (int u = 0; u < 4; ++u) {
            int v  = tid + 256 * u;          // float4 index 0..1023
            int sl = v >> 9;
            int rm = v & 511;
            int b  = rm >> 6, j4 = rm & 63;
            float4 x = seq4[((size_t)b * SS + s0 + sl) * 64 + j4];
            ((float4*)xs)[v] = x;
            unsigned* dst = (unsigned*)&xsb[sl * 8 + b][4 * j4];
            dst[0] = bf16pair(x.x, x.y);
            dst[1] = bf16pair(x.z, x.w);
        }
    }
    __syncthreads();

    #pragma unroll 1
    for (int layer = 0; layer < 2; ++layer) {
        const float* M  = layer ? M2  : M1;
        const float* P  = layer ? P2  : P1;
        const float* g  = layer ? g2  : g1;
        const float* be = layer ? be2 : be1;

        // ======== phase A: xt = x @ M^T (MFMA), wave owns n-tiles 4w..4w+3
        float4v acc1[4];
        #pragma unroll
        for (int nt = 0; nt < 4; ++nt) acc1[nt] = (float4v){0.f, 0.f, 0.f, 0.f};

        #pragma unroll 1
        for (int kt = 0; kt < 8; ++kt) {
            short8 a = *(const short8*)&xsb[l15][kt * 32 + quad * 8];
            #pragma unroll
            for (int nt = 0; nt < 4; ++nt) {
                int n0 = 16 * (4 * w + nt);
                const float4* Mr = (const float4*)M +
                    ((size_t)(n0 + l15) * 64 + kt * 8 + quad * 2);
                float4 m0 = Mr[0], m1 = Mr[1];
                union { short8 s; unsigned u[4]; } bb;
                bb.u[0] = bf16pair(m0.x, m0.y);
                bb.u[1] = bf16pair(m0.z, m0.w);
                bb.u[2] = bf16pair(m1.x, m1.y);
                bb.u[3] = bf16pair(m1.z, m1.w);
                acc1[nt] = __builtin_amdgcn_mfma_f32_16x16x32_bf16(a, bb.s, acc1[nt], 0, 0, 0);
            }
        }

        // ======== LayerNorm in C-register layout (row m = quad*4+reg)
        {
            float rsum[4], rssq[4];
            #pragma unroll
            for (int reg = 0; reg < 4; ++reg) {
                float sm = 0.f, sq = 0.f;
                #pragma unroll
                for (int nt = 0; nt < 4; ++nt) {
                    float v = acc1[nt][reg];
                    sm += v;
                    sq  = fmaf(v, v, sq);
                }
                #pragma unroll
                for (int off = 1; off < 16; off <<= 1) {
                    sm += __shfl_xor(sm, off, 64);
                    sq += __shfl_xor(sq, off, 64);
                }
                rsum[reg] = sm; rssq[reg] = sq;
            }
            if (l15 == 0) {
                #pragma unroll
                for (int reg = 0; reg < 4; ++reg) {
                    stats[w][quad * 4 + reg][0] = rsum[reg];
                    stats[w][quad * 4 + reg][1] = rssq[reg];
                }
            }
        }
        __syncthreads();
        {
            float mu[4], rs[4];
            #pragma unroll
            for (int reg = 0; reg < 4; ++reg) {
                int m = quad * 4 + reg;
                float sm = stats[0][m][0] + stats[1][m][0] + stats[2][m][0] + stats[3][m][0];
                float sq = stats[0][m][1] + stats[1][m][1] + stats[2][m][1] + stats[3][m][1];
                float mm = sm * (1.f / DD);
                mu[reg] = mm;
                rs[reg] = rsqrtf(sq * (1.f / DD) - mm * mm + 1e-5f);
            }
            #pragma unroll
            for (int nt = 0; nt < 4; ++nt) {
                int col = 16 * (4 * w + nt) + l15;
                float gv = g[col], bv = be[col];
                #pragma unroll
                for (int reg = 0; reg < 4; ++reg) {
                    float v = fmaf((acc1[nt][reg] - mu[reg]) * rs[reg], gv, bv);
                    xtb[quad * 4 + reg][col] = bf16one(v);
                }
            }
        }
        __syncthreads();   // xtb ready for phase B

        // ======== phase B: Nk = xt @ W_s^T, B-frags generated in registers
        float4v accS[2][4];
        #pragma unroll
        for (int sl = 0; sl < 2; ++sl)
            #pragma unroll
            for (int nt = 0; nt < 4; ++nt) accS[sl][nt] = (float4v){0.f, 0.f, 0.f, 0.f};

        #pragma unroll 1
        for (int kt = 0; kt < 8; ++kt) {
            short8 a = *(const short8*)&xtb[l15][kt * 32 + quad * 8];
            const int jb = kt * 32 + quad * 8;
            #pragma unroll
            for (int nt = 0; nt < 4; ++nt) {
                const int n = 16 * (4 * w + nt) + l15;     // W row (output col i)
                const float4* Pr = (const float4*)(P + (size_t)n * DD + jb);
                float4 p0 = Pr[0], p1 = Pr[1];
                const float pbase = (float)(n * DD + jb + 2);
                float pe[8] = {p0.x, p0.y, p0.z, p0.w, p1.x, p1.y, p1.z, p1.w};
                float w0[8], w1[8];
                #pragma unroll
                for (int e = 0; e < 8; ++e) {
                    float invp = __builtin_amdgcn_rcpf(pbase + (float)e);
                    w0[e] = pe[e] * __builtin_amdgcn_cosf(__builtin_amdgcn_fractf(k0 * invp));
                    w1[e] = pe[e] * __builtin_amdgcn_cosf(__builtin_amdgcn_fractf(k1 * invp));
                }
                union { short8 s; unsigned u[4]; } b0, b1;
                #pragma unroll
                for (int e = 0; e < 4; ++e) {
                    b0.u[e] = bf16pair(w0[2 * e], w0[2 * e + 1]);
                    b1.u[e] = bf16pair(w1[2 * e], w1[2 * e + 1]);
                }
                accS[0][nt] = __builtin_amdgcn_mfma_f32_16x16x32_bf16(a, b0.s, accS[0][nt], 0, 0, 0);
                accS[1][nt] = __builtin_amdgcn_mfma_f32_16x16x32_bf16(a, b1.s, accS[1][nt], 0, 0, 0);
            }
        }

        // ======== epilogue: select valid s-half per quad, add residual
        #pragma unroll
        for (int nt = 0; nt < 4; ++nt) {
            int col = 16 * (4 * w + nt) + l15;
            float4v av = (quad < 2) ? accS[0][nt] : accS[1][nt];
            int sl = quad >> 1;
            #pragma unroll
            for (int reg = 0; reg < 4; ++reg) {
                int m = quad * 4 + reg;
                int b = m & 7;
                float val = av[reg] + xs[sl][b][col];
                if (layer == 0) {
                    xs[sl][b][col] = val;
                    xsb[m][col]    = bf16one(val);
                } else {
                    out[((size_t)b * SS + s0 + sl) * DD + col] = val;
                }
            }
        }
        if (layer == 0) __syncthreads();
    }
}

extern "C" void kernel_launch(void* const* d_in, const int* in_sizes, int n_in,
                              void* d_out, int out_size, void* d_ws, size_t ws_size,
                              hipStream_t stream)
{
    const float* seq = (const float*)d_in[0];
    const float* M1  = (const float*)d_in[1];
    const float* P1  = (const float*)d_in[2];
    const float* g1  = (const float*)d_in[3];
    const float* b1  = (const float*)d_in[4];
    const float* M2  = (const float*)d_in[5];
    const float* P2  = (const float*)d_in[6];
    const float* g2  = (const float*)d_in[7];
    const float* b2  = (const float*)d_in[8];
    float* out = (float*)d_out;

    fused_hierddpm<<<SS / 2, 256, 0, stream>>>(seq, M1, P1, g1, b1,
                                               M2, P2, g2, b2, out);
}

// Round 6
// 143.546 us; speedup vs baseline: 2.9676x; 1.1042x over previous
//
#include <hip/hip_runtime.h>

#define DD 256
#define BB 8
#define SS 1024
#define XSTRIDE 264

typedef __attribute__((ext_vector_type(8))) short short8;
typedef __attribute__((ext_vector_type(4))) float float4v;

// round-to-nearest-even fp32 -> bf16 pair packed into u32 (a=low, b=high)
__device__ __forceinline__ unsigned bf16pair(float a, float b) {
    unsigned ua = __float_as_uint(a), ub = __float_as_uint(b);
    ua += 0x7FFFu + ((ua >> 16) & 1u);
    ub += 0x7FFFu + ((ub >> 16) & 1u);
    return (ua >> 16) | (ub & 0xFFFF0000u);
}
__device__ __forceinline__ unsigned short bf16one(float a) {
    unsigned ua = __float_as_uint(a);
    ua += 0x7FFFu + ((ua >> 16) & 1u);
    return (unsigned short)(ua >> 16);
}

// Block = 512 threads (8 waves), handles s0=2*bid and s0+1. Grid 512 = 2 blocks/CU.
// A rows r = sl*8+b (16). Wave w owns n-tiles 2w, 2w+1 (24 acc regs total -> no spill).
// Phase B: W_s B-frags generated in registers; P prefetched 1 kt ahead.
__global__ __launch_bounds__(512, 4)
void fused_hierddpm(const float* __restrict__ seq,
                    const float* __restrict__ M1, const float* __restrict__ P1,
                    const float* __restrict__ g1, const float* __restrict__ be1,
                    const float* __restrict__ M2, const float* __restrict__ P2,
                    const float* __restrict__ g2, const float* __restrict__ be2,
                    float* __restrict__ out)
{
    __shared__ float xs[2][BB][DD];                           // 16384 B residual fp32
    __shared__ __align__(16) unsigned short xsb[16][XSTRIDE]; // 8448 B input bf16 (A-layout)
    __shared__ __align__(16) unsigned short xtb[16][XSTRIDE]; // 8448 B LN'd xt bf16
    __shared__ float stats[8][16][2];                         // 1024 B

    const int tid  = threadIdx.x;
    const int w    = tid >> 6;
    const int lane = tid & 63;
    const int l15  = lane & 15;
    const int quad = lane >> 4;
    const int s0   = blockIdx.x * 2;
    const float k0 = (float)s0, k1 = (float)(s0 + 1);

    // ---- stage x into xs (fp32) and xsb (bf16 A-layout rows r = sl*8+b)
    {
        const float4* seq4 = (const float4*)seq;
        #pragma unroll
        for (int u = 0; u < 2; ++u) {
            int v  = tid + 512 * u;          // float4 index 0..1023
            int sl = v >> 9;
            int rm = v & 511;
            int b  = rm >> 6, j4 = rm & 63;
            float4 x = seq4[((size_t)b * SS + s0 + sl) * 64 + j4];
            ((float4*)xs)[v] = x;
            unsigned* dst = (unsigned*)&xsb[sl * 8 + b][4 * j4];
            dst[0] = bf16pair(x.x, x.y);
            dst[1] = bf16pair(x.z, x.w);
        }
    }
    __syncthreads();

    #pragma unroll 1
    for (int layer = 0; layer < 2; ++layer) {
        const float* M  = layer ? M2  : M1;
        const float* P  = layer ? P2  : P1;
        const float* g  = layer ? g2  : g1;
        const float* be = layer ? be2 : be1;

        // ======== phase A: xt = x @ M^T (MFMA); wave owns n-tiles 2w, 2w+1
        float4v acc1[2];
        acc1[0] = (float4v){0.f, 0.f, 0.f, 0.f};
        acc1[1] = (float4v){0.f, 0.f, 0.f, 0.f};

        #pragma unroll 1
        for (int kt = 0; kt < 8; ++kt) {
            short8 a = *(const short8*)&xsb[l15][kt * 32 + quad * 8];
            #pragma unroll
            for (int t = 0; t < 2; ++t) {
                int n0 = 16 * (2 * w + t);
                const float4* Mr = (const float4*)M +
                    ((size_t)(n0 + l15) * 64 + kt * 8 + quad * 2);
                float4 m0 = Mr[0], m1 = Mr[1];
                union { short8 s; unsigned u[4]; } bb;
                bb.u[0] = bf16pair(m0.x, m0.y);
                bb.u[1] = bf16pair(m0.z, m0.w);
                bb.u[2] = bf16pair(m1.x, m1.y);
                bb.u[3] = bf16pair(m1.z, m1.w);
                acc1[t] = __builtin_amdgcn_mfma_f32_16x16x32_bf16(a, bb.s, acc1[t], 0, 0, 0);
            }
        }

        // ======== LayerNorm in C-register layout (row m = quad*4+reg)
        {
            #pragma unroll
            for (int reg = 0; reg < 4; ++reg) {
                float sm = acc1[0][reg] + acc1[1][reg];
                float sq = fmaf(acc1[0][reg], acc1[0][reg], acc1[1][reg] * acc1[1][reg]);
                #pragma unroll
                for (int off = 1; off < 16; off <<= 1) {
                    sm += __shfl_xor(sm, off, 64);
                    sq += __shfl_xor(sq, off, 64);
                }
                if (l15 == 0) {
                    stats[w][quad * 4 + reg][0] = sm;
                    stats[w][quad * 4 + reg][1] = sq;
                }
            }
        }
        __syncthreads();
        {
            float mu[4], rs[4];
            #pragma unroll
            for (int reg = 0; reg < 4; ++reg) {
                int m = quad * 4 + reg;
                float sm = 0.f, sq = 0.f;
                #pragma unroll
                for (int ww = 0; ww < 8; ++ww) {
                    sm += stats[ww][m][0];
                    sq += stats[ww][m][1];
                }
                float mm = sm * (1.f / DD);
                mu[reg] = mm;
                rs[reg] = rsqrtf(sq * (1.f / DD) - mm * mm + 1e-5f);
            }
            #pragma unroll
            for (int t = 0; t < 2; ++t) {
                int col = 16 * (2 * w + t) + l15;
                float gv = g[col], bv = be[col];
                #pragma unroll
                for (int reg = 0; reg < 4; ++reg) {
                    float v = fmaf((acc1[t][reg] - mu[reg]) * rs[reg], gv, bv);
                    xtb[quad * 4 + reg][col] = bf16one(v);
                }
            }
        }
        __syncthreads();   // xtb ready for phase B

        // ======== phase B: Nk = xt @ W_s^T, B-frags in registers, P prefetched
        float4v accS[2][2];
        #pragma unroll
        for (int sl = 0; sl < 2; ++sl)
            #pragma unroll
            for (int t = 0; t < 2; ++t) accS[sl][t] = (float4v){0.f, 0.f, 0.f, 0.f};

        const float4* P4 = (const float4*)P;
        const int n_0 = 16 * (2 * w + 0) + l15;
        const int n_1 = 16 * (2 * w + 1) + l15;
        // current kt=0 P data
        float4 pa0 = P4[(size_t)n_0 * 64 + quad * 2];
        float4 pb0 = P4[(size_t)n_0 * 64 + quad * 2 + 1];
        float4 pa1 = P4[(size_t)n_1 * 64 + quad * 2];
        float4 pb1 = P4[(size_t)n_1 * 64 + quad * 2 + 1];

        #pragma unroll 1
        for (int kt = 0; kt < 8; ++kt) {
            // prefetch next kt (kt=7 re-fetches kt=0; harmless L1/L2 hit)
            const int ktn = (kt + 1) & 7;
            float4 qa0 = P4[(size_t)n_0 * 64 + ktn * 8 + quad * 2];
            float4 qb0 = P4[(size_t)n_0 * 64 + ktn * 8 + quad * 2 + 1];
            float4 qa1 = P4[(size_t)n_1 * 64 + ktn * 8 + quad * 2];
            float4 qb1 = P4[(size_t)n_1 * 64 + ktn * 8 + quad * 2 + 1];

            short8 a = *(const short8*)&xtb[l15][kt * 32 + quad * 8];

            #pragma unroll
            for (int t = 0; t < 2; ++t) {
                const int n = t ? n_1 : n_0;
                const float4 pa = t ? pa1 : pa0;
                const float4 pb = t ? pb1 : pb0;
                const float pbase = (float)(n * DD + kt * 32 + quad * 8 + 2);
                float pe[8] = {pa.x, pa.y, pa.z, pa.w, pb.x, pb.y, pb.z, pb.w};
                float w0[8], w1[8];
                #pragma unroll
                for (int e = 0; e < 8; ++e) {
                    float invp = __builtin_amdgcn_rcpf(pbase + (float)e);
                    w0[e] = pe[e] * __builtin_amdgcn_cosf(__builtin_amdgcn_fractf(k0 * invp));
                    w1[e] = pe[e] * __builtin_amdgcn_cosf(__builtin_amdgcn_fractf(k1 * invp));
                }
                union { short8 s; unsigned u[4]; } b0, b1;
                #pragma unroll
                for (int e = 0; e < 4; ++e) {
                    b0.u[e] = bf16pair(w0[2 * e], w0[2 * e + 1]);
                    b1.u[e] = bf16pair(w1[2 * e], w1[2 * e + 1]);
                }
                accS[0][t] = __builtin_amdgcn_mfma_f32_16x16x32_bf16(a, b0.s, accS[0][t], 0, 0, 0);
                accS[1][t] = __builtin_amdgcn_mfma_f32_16x16x32_bf16(a, b1.s, accS[1][t], 0, 0, 0);
            }
            pa0 = qa0; pb0 = qb0; pa1 = qa1; pb1 = qb1;
        }

        // ======== epilogue: select valid s-half per quad, add residual
        #pragma unroll
        for (int t = 0; t < 2; ++t) {
            int col = 16 * (2 * w + t) + l15;
            float4v av = (quad < 2) ? accS[0][t] : accS[1][t];
            int sl = quad >> 1;
            #pragma unroll
            for (int reg = 0; reg < 4; ++reg) {
                int m = quad * 4 + reg;
                int b = m & 7;
                float val = av[reg] + xs[sl][b][col];
                if (layer == 0) {
                    xs[sl][b][col] = val;
                    xsb[m][col]    = bf16one(val);
                } else {
                    out[((size_t)b * SS + s0 + sl) * DD + col] = val;
                }
            }
        }
        if (layer == 0) __syncthreads();
    }
}

extern "C" void kernel_launch(void* const* d_in, const int* in_sizes, int n_in,
                              void* d_out, int out_size, void* d_ws, size_t ws_size,
                              hipStream_t stream)
{
    const float* seq = (const float*)d_in[0];
    const float* M1  = (const float*)d_in[1];
    const float* P1  = (const float*)d_in[2];
    const float* g1  = (const float*)d_in[3];
    const float* b1  = (const float*)d_in[4];
    const float* M2  = (const float*)d_in[5];
    const float* P2  = (const float*)d_in[6];
    const float* g2  = (const float*)d_in[7];
    const float* b2  = (const float*)d_in[8];
    float* out = (float*)d_out;

    fused_hierddpm<<<SS / 2, 512, 0, stream>>>(seq, M1, P1, g1, b1,
                                               M2, P2, g2, b2, out);
}